// Round 5
// baseline (383.178 us; speedup 1.0000x reference)
//
#include <hip/hip_runtime.h>
#include <hip/hip_bf16.h>

// B=8192, A=8, OBS=128, NACT=32, H=256, D=64 ; N = 65536 rows
typedef __attribute__((ext_vector_type(8))) short bf16x8;   // 8 bf16 (4 VGPRs)
typedef __attribute__((ext_vector_type(4))) float f32x4;

#define MFMA(A, B, C) __builtin_amdgcn_mfma_f32_16x16x32_bf16((A), (B), (C), 0, 0, 0)

// ---- ws byte offsets: weights pre-split to bf16 hi/lo planes, [out][k] layout ----
#define OFF_TB    0          // f32 [32]   folded t bias
#define OFF_WT_H  128        // bf16 [32][256]  Mt = SCALE*wk^T*wq
#define OFF_WT_L  16512
#define OFF_WHV_H 32896      // bf16 [64][256]  wv1 h-part
#define OFF_WHV_L 65664
#define OFF_WA_H  98432      // bf16 [64][32]   wv1 action-part
#define OFF_WA_L  102528     // end 106624

// ---- LDS (bytes), total 7168 = 2 waves x {HV 2176 + AT 256 + SS 1152} ----
// Round 5: 8 rows (one batch) per wave, 2 independent waves per 128-thr WG,
// grid 4096 -> 8192 waves = 32 waves/CU (was 16, grid-limited). Phase A
// duplicates rows across l15 0-7 / 8-15 (same addrs, benign); phase B/SS
// partition exactly (4 nt batches, hrow == jB since wave == one batch).
#define SM_HV   0        // f32 [2][8][68]    4352
#define SM_AT   4352     // f32 [2][8][8]      512
#define SM_SS   4864     // bf16 [2][8][72]   2304  (stride 72: rows 16B-aligned)
#define SM_TOT  7168

__device__ __forceinline__ unsigned short f2bf(float v) {   // RNE (setup only)
    unsigned u = __builtin_bit_cast(unsigned, v);
    return (unsigned short)((u + 0x7fffu + ((u >> 16) & 1u)) >> 16);
}
__device__ __forceinline__ float bf2f(unsigned short b) {
    return __builtin_bit_cast(float, ((unsigned)b) << 16);
}
__device__ __forceinline__ ushort2 splitf(float v) {        // (hi, lo residual)
    unsigned short h = f2bf(v);
    unsigned short l = f2bf(v - bf2f(h));
    return make_ushort2(h, l);
}

// __hip_bfloat162 -> u32 reinterpret (bit_cast rejects non-trivially-copyable)
__device__ __forceinline__ unsigned as_u32(__hip_bfloat162 v) {
    unsigned u;
    __builtin_memcpy(&u, &v, sizeof(u));
    return u;
}

// fast split via packed f32->bf16 convert (RNE, identical numerics to f2bf)
__device__ __forceinline__ void split2(float x, float y, unsigned& h, unsigned& l) {
    __hip_bfloat162 h2 = __float22bfloat162_rn(make_float2(x, y));
    float2 hf = __bfloat1622float2(h2);
    __hip_bfloat162 l2 = __float22bfloat162_rn(make_float2(x - hf.x, y - hf.y));
    h = as_u32(h2);
    l = as_u32(l2);
}
__device__ __forceinline__ void split8(float4 a, float4 b, bf16x8& hi, bf16x8& lo) {
    uint4 H, L;
    split2(a.x, a.y, H.x, L.x);
    split2(a.z, a.w, H.y, L.y);
    split2(b.x, b.y, H.z, L.z);
    split2(b.z, b.w, H.w, L.w);
    hi = __builtin_bit_cast(bf16x8, H);
    lo = __builtin_bit_cast(bf16x8, L);
}
__device__ __forceinline__ unsigned pk2(float x, float y) {
    return as_u32(__float22bfloat162_rn(make_float2(x, y)));
}

// ---------------------------------------------------------------------------
// setup: fold Mt = SCALE*wk^T*wq (+bias), split all weights into bf16 hi/lo
// planes in fragment-native [out][k] layout. wk_b dropped (softmax-invariant,
// diagonal masked — verified round 1).
// ---------------------------------------------------------------------------
__global__ __launch_bounds__(256) void k_setup(const float* __restrict__ wq_w,
                                               const float* __restrict__ wq_b,
                                               const float* __restrict__ wk_w,
                                               const float* __restrict__ wv1,
                                               char* __restrict__ ws) {
    int gid = blockIdx.x * 256 + threadIdx.x;
    if (gid < 8192) {                              // Mt[k][c]
        int k = gid >> 8, c = gid & 255;
        float acc = 0.f;
#pragma unroll 8
        for (int d = 0; d < 64; ++d) acc = fmaf(wk_w[d * 32 + k], wq_w[d * 256 + c], acc);
        ushort2 s = splitf(0.125f * acc);
        ((unsigned short*)(ws + OFF_WT_H))[gid] = s.x;
        ((unsigned short*)(ws + OFF_WT_L))[gid] = s.y;
    } else if (gid < 24576) {                      // wv1 h-part [d][c]
        int i = gid - 8192;
        ushort2 s = splitf(wv1[(i >> 8) * 288 + (i & 255)]);
        ((unsigned short*)(ws + OFF_WHV_H))[i] = s.x;
        ((unsigned short*)(ws + OFF_WHV_L))[i] = s.y;
    } else if (gid < 26624) {                      // wv1 action-part [d][k]
        int i = gid - 24576;
        ushort2 s = splitf(wv1[(i >> 5) * 288 + 256 + (i & 31)]);
        ((unsigned short*)(ws + OFF_WA_H))[i] = s.x;
        ((unsigned short*)(ws + OFF_WA_L))[i] = s.y;
    } else if (gid < 26656) {                      // tb
        int k = gid - 26624;
        float b = 0.f;
#pragma unroll 8
        for (int d = 0; d < 64; ++d) b = fmaf(wk_w[d * 32 + k], wq_b[d], b);
        ((float*)(ws + OFF_TB))[k] = 0.125f * b;
    }
}

// ---------------------------------------------------------------------------
// Fused. Wave = 8 rows = ONE batch; WG = 2 independent waves (separate LDS
// tiles), grid 4096 -> 32 waves/CU. Split-bf16 MFMA (AhBh+AhBl+AlBh).
// __launch_bounds__(128,8) pins VGPR<=64 (8 waves/SIMD).
// ---------------------------------------------------------------------------
__global__ __launch_bounds__(128, 8) void fused(
    const float* __restrict__ o, const float* __restrict__ onx,
    const float* __restrict__ h, const float* __restrict__ act,
    const float* __restrict__ wv1b, const float* __restrict__ wv2,
    const float* __restrict__ wv2b, const char* __restrict__ ws,
    float* __restrict__ out)
{
    __shared__ __align__(16) char sm[SM_TOT];

    const int tid  = threadIdx.x;
    const int wid  = tid >> 6;             // 0/1: which 8-row half
    const int lane = tid & 63;
    const int l15  = lane & 15;
    const int quad = lane >> 4;
    const int r8   = l15 & 7;              // row within this wave's batch
    const int n0   = blockIdx.x * 16 + wid * 8;   // wave's batch base row
    const int myrow = n0 + r8;             // phase-A fragment row (l15 8-15 dup)

    float* HV = (float*)(sm + SM_HV) + wid * 544;           // [8][68]
    float* AT = (float*)(sm + SM_AT) + wid * 64;            // [8][8]
    unsigned short* SS = (unsigned short*)(sm + SM_SS) + wid * 576;  // [8][72]

    const f32x4 zv = {0.f, 0.f, 0.f, 0.f};
    f32x4 acc_hv[4] = {zv, zv, zv, zv};
    f32x4 acc_t[2]  = {zv, zv};

    // ---- Phase A-x: preload all 8 chunks, then MFMA ----
    float4 xa[8], xb[8];
#pragma unroll
    for (int ch = 0; ch < 8; ++ch) {
        const float* src = (ch < 4)
            ? o   + (size_t)myrow * 128 + ch * 32 + quad * 8
            : onx + (size_t)myrow * 128 + (ch - 4) * 32 + quad * 8;
        xa[ch] = ((const float4*)src)[0];
        xb[ch] = ((const float4*)src)[1];
    }
#pragma unroll
    for (int ch = 0; ch < 8; ++ch) {
        bf16x8 Bh, Bl;
        split8(xa[ch], xb[ch], Bh, Bl);
#pragma unroll
        for (int mt = 0; mt < 2; ++mt) {
            int off = ((mt * 16 + l15) * 256 + ch * 32 + quad * 8) * 2;
            bf16x8 Ah = *(const bf16x8*)(ws + OFF_WT_H + off);
            bf16x8 Al = *(const bf16x8*)(ws + OFF_WT_L + off);
            acc_t[mt] = MFMA(Ah, Bh, acc_t[mt]);
            acc_t[mt] = MFMA(Ah, Bl, acc_t[mt]);
            acc_t[mt] = MFMA(Al, Bh, acc_t[mt]);
        }
    }
    // ---- Phase A-h ----
#pragma unroll
    for (int ch = 0; ch < 8; ++ch) {
        const float* src = h + (size_t)myrow * 256 + ch * 32 + quad * 8;
        xa[ch] = ((const float4*)src)[0];
        xb[ch] = ((const float4*)src)[1];
    }
#pragma unroll
    for (int ch = 0; ch < 8; ++ch) {
        bf16x8 Bh, Bl;
        split8(xa[ch], xb[ch], Bh, Bl);
#pragma unroll
        for (int mt = 0; mt < 4; ++mt) {
            int off = ((mt * 16 + l15) * 256 + ch * 32 + quad * 8) * 2;
            bf16x8 Ah = *(const bf16x8*)(ws + OFF_WHV_H + off);
            bf16x8 Al = *(const bf16x8*)(ws + OFF_WHV_L + off);
            acc_hv[mt] = MFMA(Ah, Bh, acc_hv[mt]);
            acc_hv[mt] = MFMA(Ah, Bl, acc_hv[mt]);
            acc_hv[mt] = MFMA(Al, Bh, acc_hv[mt]);
        }
    }

    // ---- scores act preload (latency hides under HV epilogue) ----
    const float* arow = act + (size_t)myrow * 256;
    float4 av0[8], av1[8];
#pragma unroll
    for (int j = 0; j < 8; ++j) {
        av0[j] = *(const float4*)(arow + j * 32 + quad * 4);
        av1[j] = *(const float4*)(arow + j * 32 + 16 + quad * 4);
    }

    // ---- epilogue A: HV to LDS (col=l15 -> row n, row=quad*4+reg -> d) ----
    if (l15 < 8) {
#pragma unroll
        for (int mt = 0; mt < 4; ++mt) {
            int d0 = mt * 16 + quad * 4;
            float4 b = *(const float4*)&wv1b[d0];
            f32x4 a = acc_hv[mt];
            *(float4*)&HV[r8 * 68 + d0] =
                make_float4(a[0] + b.x, a[1] + b.y, a[2] + b.z, a[3] + b.w);
        }
    }

    // ---- scores + softmax fully in-register ----
    {
        float t8[8];
        const float* tb = (const float*)(ws + OFF_TB);
#pragma unroll
        for (int mt = 0; mt < 2; ++mt) {
            float4 b = *(const float4*)&tb[mt * 16 + quad * 4];
            t8[mt * 4 + 0] = acc_t[mt][0] + b.x;
            t8[mt * 4 + 1] = acc_t[mt][1] + b.y;
            t8[mt * 4 + 2] = acc_t[mt][2] + b.z;
            t8[mt * 4 + 3] = acc_t[mt][3] + b.w;
        }
        float sc[8];
#pragma unroll
        for (int j = 0; j < 8; ++j) {
            float s = 0.f;
            s = fmaf(t8[0], av0[j].x, s);
            s = fmaf(t8[1], av0[j].y, s);
            s = fmaf(t8[2], av0[j].z, s);
            s = fmaf(t8[3], av0[j].w, s);
            s = fmaf(t8[4], av1[j].x, s);
            s = fmaf(t8[5], av1[j].y, s);
            s = fmaf(t8[6], av1[j].z, s);
            s = fmaf(t8[7], av1[j].w, s);
            sc[j] = s;
        }
#pragma unroll
        for (int j = 0; j < 8; ++j) {        // sum partials across the 4 quads
            sc[j] += __shfl_xor(sc[j], 16);
            sc[j] += __shfl_xor(sc[j], 32);
        }
        const int diag = r8;                 // block row == agent index in batch
        float mx = -1e30f;
#pragma unroll
        for (int j = 0; j < 8; ++j) if (j != diag) mx = fmaxf(mx, sc[j]);
        float ex[8], sum = 0.f;
#pragma unroll
        for (int j = 0; j < 8; ++j) {
            ex[j] = (j == diag) ? 0.f : __expf(sc[j] - mx);
            sum += ex[j];
        }
        float inv = 1.f / sum;
        if (lane < 8) {                      // one writer per row (quad0, l15<8)
            *(float4*)&AT[lane * 8] =
                make_float4(ex[0] * inv, ex[1] * inv, ex[2] * inv, ex[3] * inv);
            *(float4*)&AT[lane * 8 + 4] =
                make_float4(ex[4] * inv, ex[5] * inv, ex[6] * inv, ex[7] * inv);
        }
    }

    // hoist phase-B A-frags
    bf16x8 WAh[4], WAl[4];
#pragma unroll
    for (int mt = 0; mt < 4; ++mt) {
        int off = ((mt * 16 + l15) * 32 + quad * 8) * 2;
        WAh[mt] = *(const bf16x8*)(ws + OFF_WA_H + off);
        WAl[mt] = *(const bf16x8*)(ws + OFF_WA_L + off);
    }
    __syncthreads();                         // HV/AT visible (2 symmetric waves)

    // ---- Phase B: 8 rows x 8 j = 64 pairs, 4 MFMA batches ----
    // pair = nt*16 + l15 ; nb = nt*2 + (l15>>3) in [0,8), j = l15&7
    const int jB  = l15 & 7;
    const int nbh = l15 >> 3;
    {
        float4 bv0[4], bv1[4];
#pragma unroll
        for (int ii = 0; ii < 4; ++ii) {
            int nb = ii * 2 + nbh;
            const float* ap = act + (size_t)(n0 + nb) * 256 + jB * 32 + quad * 8;
            bv0[ii] = ((const float4*)ap)[0];
            bv1[ii] = ((const float4*)ap)[1];
        }
#pragma unroll
        for (int ii = 0; ii < 4; ++ii) {
            int nb = ii * 2 + nbh;
            bf16x8 Bh, Bl;
            split8(bv0[ii], bv1[ii], Bh, Bl);
            f32x4 accB[4] = {zv, zv, zv, zv};
#pragma unroll
            for (int mt = 0; mt < 4; ++mt) {
                accB[mt] = MFMA(WAh[mt], Bh, accB[mt]);
                accB[mt] = MFMA(WAh[mt], Bl, accB[mt]);
                accB[mt] = MFMA(WAl[mt], Bh, accB[mt]);
            }
            float at = AT[nb * 8 + jB];
#pragma unroll
            for (int mt = 0; mt < 4; ++mt) {
                int d0 = mt * 16 + quad * 4;
                float4 hv4 = *(const float4*)&HV[jB * 68 + d0];   // h_rep row = j
                float r0 = at * fmaxf(accB[mt][0] + hv4.x, 0.f);
                float r1 = at * fmaxf(accB[mt][1] + hv4.y, 0.f);
                float r2 = at * fmaxf(accB[mt][2] + hv4.z, 0.f);
                float r3 = at * fmaxf(accB[mt][3] + hv4.w, 0.f);
#pragma unroll
                for (int m = 1; m <= 4; m <<= 1) {
                    r0 += __shfl_xor(r0, m);
                    r1 += __shfl_xor(r1, m);
                    r2 += __shfl_xor(r2, m);
                    r3 += __shfl_xor(r3, m);
                }
                if (jB == 0)                 // S row nb, d0..d0+3, bf16-packed
                    *(uint2*)&SS[nb * 72 + d0] = make_uint2(pk2(r0, r1), pk2(r2, r3));
            }
        }
    }

    // ---- W2 fragment loads (4KB shared, L2-hot) ----
    float4 wva[4], wvb[4];                   // c = et*2 + kc
#pragma unroll
    for (int c = 0; c < 4; ++c) {
        const float* wp = wv2 + ((c >> 1) * 16 + l15) * 64 + (c & 1) * 32 + quad * 8;
        wva[c] = ((const float4*)wp)[0];
        wvb[c] = ((const float4*)wp)[1];
    }
    __syncthreads();                         // SS visible

    // ---- Wv2 via MFMA: out[8x32] = S[8x64] . W2^T (B rows 8-15 dup) ----
    {
        bf16x8 Sb[2];
#pragma unroll
        for (int kc = 0; kc < 2; ++kc)
            Sb[kc] = *(const bf16x8*)&SS[r8 * 72 + kc * 32 + quad * 8];
        f32x4 acc2[2] = {zv, zv};
#pragma unroll
        for (int c = 0; c < 4; ++c) {
            bf16x8 Ah, Al;
            split8(wva[c], wvb[c], Ah, Al);
            acc2[c >> 1] = MFMA(Ah, Sb[c & 1], acc2[c >> 1]);
            acc2[c >> 1] = MFMA(Al, Sb[c & 1], acc2[c >> 1]);
        }
        if (l15 < 8) {
#pragma unroll
            for (int et = 0; et < 2; ++et) {
                int e0 = et * 16 + quad * 4;
                float4 b = *(const float4*)&wv2b[e0];
                f32x4 a = acc2[et];
                *(float4*)&out[(size_t)(n0 + r8) * 32 + e0] =
                    make_float4(a[0] + b.x, a[1] + b.y, a[2] + b.z, a[3] + b.w);
            }
        }
    }
}

extern "C" void kernel_launch(void* const* d_in, const int* in_sizes, int n_in,
                              void* d_out, int out_size, void* d_ws, size_t ws_size,
                              hipStream_t stream) {
    const float* o     = (const float*)d_in[0];
    const float* onx   = (const float*)d_in[1];
    const float* h     = (const float*)d_in[2];
    const float* act   = (const float*)d_in[3];
    const float* wq_w  = (const float*)d_in[4];
    const float* wq_b  = (const float*)d_in[5];
    const float* wk_w  = (const float*)d_in[6];
    // d_in[7] = wk_b unused (softmax-invariant, diagonal masked)
    const float* wv1_w = (const float*)d_in[8];
    const float* wv1_b = (const float*)d_in[9];
    const float* wv2_w = (const float*)d_in[10];
    const float* wv2_b = (const float*)d_in[11];
    float* out = (float*)d_out;
    char* ws   = (char*)d_ws;   // needs ~105 KB

    k_setup<<<105, 256, 0, stream>>>(wq_w, wq_b, wk_w, wv1_w, ws);
    fused<<<4096, 128, 0, stream>>>(o, onx, h, act, wv1_b, wv2_w, wv2_b, ws, out);
}

// Round 7
// 303.592 us; speedup vs baseline: 1.2621x; 1.2621x over previous
//
#include <hip/hip_runtime.h>
#include <hip/hip_bf16.h>

// B=8192, A=8, OBS=128, NACT=32, H=256, D=64 ; N = 65536 rows
typedef __attribute__((ext_vector_type(8))) short bf16x8;   // 8 bf16 (4 VGPRs)
typedef __attribute__((ext_vector_type(4))) float f32x4;

#define MFMA(A, B, C) __builtin_amdgcn_mfma_f32_16x16x32_bf16((A), (B), (C), 0, 0, 0)

// ---- ws byte offsets: weights pre-split to bf16 hi/lo planes, [out][k] layout ----
#define OFF_TB    0          // f32 [32]   folded t bias
#define OFF_WT_H  128        // bf16 [32][256]  Mt = SCALE*wk^T*wq
#define OFF_WT_L  16512
#define OFF_WHV_H 32896      // bf16 [64][256]  wv1 h-part
#define OFF_WHV_L 65664
#define OFF_WA_H  98432      // bf16 [64][32]   wv1 action-part
#define OFF_WA_L  102528     // end 106624

// ---- LDS (bytes), total 3584: single 8-row wave per WG ----
// Round 7 (= round 6 resubmitted; infra failure, never measured): keep 8-row
// waves + grid 8192 (32 waves/CU supply) but do NOT force a VGPR cap (round
// 5's (128,8) -> forced 32 VGPR -> ~380 MB spill traffic). (64,4) = the bound
// that gave spill-free VGPR=64 in round 4; live sets slimmed (4-deep
// preloads) so allocator lands ~80-96 -> 20-24 waves/CU.
#define SM_HV   0        // f32 [8][68]    2176
#define SM_AT   2176     // f32 [8][8]      256
#define SM_SS   2432     // bf16 [8][72]   1152  (stride 72: rows 16B-aligned)
#define SM_TOT  3584

__device__ __forceinline__ unsigned short f2bf(float v) {   // RNE (setup only)
    unsigned u = __builtin_bit_cast(unsigned, v);
    return (unsigned short)((u + 0x7fffu + ((u >> 16) & 1u)) >> 16);
}
__device__ __forceinline__ float bf2f(unsigned short b) {
    return __builtin_bit_cast(float, ((unsigned)b) << 16);
}
__device__ __forceinline__ ushort2 splitf(float v) {        // (hi, lo residual)
    unsigned short h = f2bf(v);
    unsigned short l = f2bf(v - bf2f(h));
    return make_ushort2(h, l);
}

// __hip_bfloat162 -> u32 reinterpret (bit_cast rejects non-trivially-copyable)
__device__ __forceinline__ unsigned as_u32(__hip_bfloat162 v) {
    unsigned u;
    __builtin_memcpy(&u, &v, sizeof(u));
    return u;
}

// fast split via packed f32->bf16 convert (RNE, identical numerics to f2bf)
__device__ __forceinline__ void split2(float x, float y, unsigned& h, unsigned& l) {
    __hip_bfloat162 h2 = __float22bfloat162_rn(make_float2(x, y));
    float2 hf = __bfloat1622float2(h2);
    __hip_bfloat162 l2 = __float22bfloat162_rn(make_float2(x - hf.x, y - hf.y));
    h = as_u32(h2);
    l = as_u32(l2);
}
__device__ __forceinline__ void split8(float4 a, float4 b, bf16x8& hi, bf16x8& lo) {
    uint4 H, L;
    split2(a.x, a.y, H.x, L.x);
    split2(a.z, a.w, H.y, L.y);
    split2(b.x, b.y, H.z, L.z);
    split2(b.z, b.w, H.w, L.w);
    hi = __builtin_bit_cast(bf16x8, H);
    lo = __builtin_bit_cast(bf16x8, L);
}
__device__ __forceinline__ unsigned pk2(float x, float y) {
    return as_u32(__float22bfloat162_rn(make_float2(x, y)));
}

// ---------------------------------------------------------------------------
// setup: fold Mt = SCALE*wk^T*wq (+bias), split all weights into bf16 hi/lo
// planes in fragment-native [out][k] layout. wk_b dropped (softmax-invariant,
// diagonal masked — verified round 1).
// ---------------------------------------------------------------------------
__global__ __launch_bounds__(256) void k_setup(const float* __restrict__ wq_w,
                                               const float* __restrict__ wq_b,
                                               const float* __restrict__ wk_w,
                                               const float* __restrict__ wv1,
                                               char* __restrict__ ws) {
    int gid = blockIdx.x * 256 + threadIdx.x;
    if (gid < 8192) {                              // Mt[k][c]
        int k = gid >> 8, c = gid & 255;
        float acc = 0.f;
#pragma unroll 8
        for (int d = 0; d < 64; ++d) acc = fmaf(wk_w[d * 32 + k], wq_w[d * 256 + c], acc);
        ushort2 s = splitf(0.125f * acc);
        ((unsigned short*)(ws + OFF_WT_H))[gid] = s.x;
        ((unsigned short*)(ws + OFF_WT_L))[gid] = s.y;
    } else if (gid < 24576) {                      // wv1 h-part [d][c]
        int i = gid - 8192;
        ushort2 s = splitf(wv1[(i >> 8) * 288 + (i & 255)]);
        ((unsigned short*)(ws + OFF_WHV_H))[i] = s.x;
        ((unsigned short*)(ws + OFF_WHV_L))[i] = s.y;
    } else if (gid < 26624) {                      // wv1 action-part [d][k]
        int i = gid - 24576;
        ushort2 s = splitf(wv1[(i >> 5) * 288 + 256 + (i & 31)]);
        ((unsigned short*)(ws + OFF_WA_H))[i] = s.x;
        ((unsigned short*)(ws + OFF_WA_L))[i] = s.y;
    } else if (gid < 26656) {                      // tb
        int k = gid - 26624;
        float b = 0.f;
#pragma unroll 8
        for (int d = 0; d < 64; ++d) b = fmaf(wk_w[d * 32 + k], wq_b[d], b);
        ((float*)(ws + OFF_TB))[k] = 0.125f * b;
    }
}

// ---------------------------------------------------------------------------
// Fused. WG = ONE wave = 8 rows = one batch; grid 8192 -> 32 waves/CU supply.
// Split-bf16 MFMA (AhBh+AhBl+AlBh). Live sets slimmed to 4-deep preload
// batches so the allocator lands <=96 VGPR without a forced cap.
// ---------------------------------------------------------------------------
__global__ __launch_bounds__(64, 4) void fused(
    const float* __restrict__ o, const float* __restrict__ onx,
    const float* __restrict__ h, const float* __restrict__ act,
    const float* __restrict__ wv1b, const float* __restrict__ wv2,
    const float* __restrict__ wv2b, const char* __restrict__ ws,
    float* __restrict__ out)
{
    __shared__ __align__(16) char sm[SM_TOT];
    float* HV = (float*)(sm + SM_HV);               // [8][68]
    float* AT = (float*)(sm + SM_AT);               // [8][8]
    unsigned short* SS = (unsigned short*)(sm + SM_SS);  // [8][72]

    const int lane = threadIdx.x;          // 0..63
    const int l15  = lane & 15;
    const int quad = lane >> 4;
    const int r8   = l15 & 7;              // row within this wave's batch
    const int n0   = blockIdx.x * 8;       // batch base row
    const int myrow = n0 + r8;             // phase-A fragment row (l15 8-15 dup)

    const f32x4 zv = {0.f, 0.f, 0.f, 0.f};
    f32x4 acc_hv[4] = {zv, zv, zv, zv};
    f32x4 acc_t[2]  = {zv, zv};

    // ---- Phase A-x: two 4-chunk batches (half0 = o, half1 = onx) ----
#pragma unroll
    for (int half = 0; half < 2; ++half) {
        const float* base = (half == 0) ? o : onx;
        float4 xa[4], xb[4];
#pragma unroll
        for (int c = 0; c < 4; ++c) {
            const float* src = base + (size_t)myrow * 128 + c * 32 + quad * 8;
            xa[c] = ((const float4*)src)[0];
            xb[c] = ((const float4*)src)[1];
        }
#pragma unroll
        for (int c = 0; c < 4; ++c) {
            int ch = half * 4 + c;         // combined k-chunk over [o|onx]
            bf16x8 Bh, Bl;
            split8(xa[c], xb[c], Bh, Bl);
#pragma unroll
            for (int mt = 0; mt < 2; ++mt) {
                int off = ((mt * 16 + l15) * 256 + ch * 32 + quad * 8) * 2;
                bf16x8 Ah = *(const bf16x8*)(ws + OFF_WT_H + off);
                bf16x8 Al = *(const bf16x8*)(ws + OFF_WT_L + off);
                acc_t[mt] = MFMA(Ah, Bh, acc_t[mt]);
                acc_t[mt] = MFMA(Ah, Bl, acc_t[mt]);
                acc_t[mt] = MFMA(Al, Bh, acc_t[mt]);
            }
        }
    }
    // ---- Phase A-h: two 4-chunk batches ----
#pragma unroll
    for (int half = 0; half < 2; ++half) {
        float4 xa[4], xb[4];
#pragma unroll
        for (int c = 0; c < 4; ++c) {
            const float* src = h + (size_t)myrow * 256 + (half * 4 + c) * 32 + quad * 8;
            xa[c] = ((const float4*)src)[0];
            xb[c] = ((const float4*)src)[1];
        }
#pragma unroll
        for (int c = 0; c < 4; ++c) {
            int ch = half * 4 + c;
            bf16x8 Bh, Bl;
            split8(xa[c], xb[c], Bh, Bl);
#pragma unroll
            for (int mt = 0; mt < 4; ++mt) {
                int off = ((mt * 16 + l15) * 256 + ch * 32 + quad * 8) * 2;
                bf16x8 Ah = *(const bf16x8*)(ws + OFF_WHV_H + off);
                bf16x8 Al = *(const bf16x8*)(ws + OFF_WHV_L + off);
                acc_hv[mt] = MFMA(Ah, Bh, acc_hv[mt]);
                acc_hv[mt] = MFMA(Ah, Bl, acc_hv[mt]);
                acc_hv[mt] = MFMA(Al, Bh, acc_hv[mt]);
            }
        }
    }

    const float* arow = act + (size_t)myrow * 256;
    float sc[8];

    // ---- scores first half: issue j0-3 loads, HV epilogue under latency ----
    {
        float4 a0[4], a1[4];
#pragma unroll
        for (int jj = 0; jj < 4; ++jj) {
            a0[jj] = *(const float4*)(arow + jj * 32 + quad * 4);
            a1[jj] = *(const float4*)(arow + jj * 32 + 16 + quad * 4);
        }

        // epilogue A: HV to LDS (col=l15 -> row n, row=quad*4+reg -> d)
        if (l15 < 8) {
#pragma unroll
            for (int mt = 0; mt < 4; ++mt) {
                int d0 = mt * 16 + quad * 4;
                float4 b = *(const float4*)&wv1b[d0];
                f32x4 a = acc_hv[mt];
                *(float4*)&HV[r8 * 68 + d0] =
                    make_float4(a[0] + b.x, a[1] + b.y, a[2] + b.z, a[3] + b.w);
            }
        }

        float t8[8];
        const float* tb = (const float*)(ws + OFF_TB);
#pragma unroll
        for (int mt = 0; mt < 2; ++mt) {
            float4 b = *(const float4*)&tb[mt * 16 + quad * 4];
            t8[mt * 4 + 0] = acc_t[mt][0] + b.x;
            t8[mt * 4 + 1] = acc_t[mt][1] + b.y;
            t8[mt * 4 + 2] = acc_t[mt][2] + b.z;
            t8[mt * 4 + 3] = acc_t[mt][3] + b.w;
        }
#pragma unroll
        for (int jj = 0; jj < 4; ++jj) {
            float s = 0.f;
            s = fmaf(t8[0], a0[jj].x, s); s = fmaf(t8[1], a0[jj].y, s);
            s = fmaf(t8[2], a0[jj].z, s); s = fmaf(t8[3], a0[jj].w, s);
            s = fmaf(t8[4], a1[jj].x, s); s = fmaf(t8[5], a1[jj].y, s);
            s = fmaf(t8[6], a1[jj].z, s); s = fmaf(t8[7], a1[jj].w, s);
            sc[jj] = s;
        }
        // second half j4-7
        float4 b0[4], b1[4];
#pragma unroll
        for (int jj = 0; jj < 4; ++jj) {
            b0[jj] = *(const float4*)(arow + (jj + 4) * 32 + quad * 4);
            b1[jj] = *(const float4*)(arow + (jj + 4) * 32 + 16 + quad * 4);
        }
#pragma unroll
        for (int jj = 0; jj < 4; ++jj) {
            float s = 0.f;
            s = fmaf(t8[0], b0[jj].x, s); s = fmaf(t8[1], b0[jj].y, s);
            s = fmaf(t8[2], b0[jj].z, s); s = fmaf(t8[3], b0[jj].w, s);
            s = fmaf(t8[4], b1[jj].x, s); s = fmaf(t8[5], b1[jj].y, s);
            s = fmaf(t8[6], b1[jj].z, s); s = fmaf(t8[7], b1[jj].w, s);
            sc[jj + 4] = s;
        }
    }

    // ---- softmax (in-register, per-lane row) ----
    {
#pragma unroll
        for (int j = 0; j < 8; ++j) {        // sum partials across the 4 quads
            sc[j] += __shfl_xor(sc[j], 16);
            sc[j] += __shfl_xor(sc[j], 32);
        }
        const int diag = r8;                 // row index within batch
        float mx = -1e30f;
#pragma unroll
        for (int j = 0; j < 8; ++j) if (j != diag) mx = fmaxf(mx, sc[j]);
        float ex[8], sum = 0.f;
#pragma unroll
        for (int j = 0; j < 8; ++j) {
            ex[j] = (j == diag) ? 0.f : __expf(sc[j] - mx);
            sum += ex[j];
        }
        float inv = 1.f / sum;
        if (lane < 8) {                      // one writer per row (quad0, l15<8)
            *(float4*)&AT[lane * 8] =
                make_float4(ex[0] * inv, ex[1] * inv, ex[2] * inv, ex[3] * inv);
            *(float4*)&AT[lane * 8 + 4] =
                make_float4(ex[4] * inv, ex[5] * inv, ex[6] * inv, ex[7] * inv);
        }
    }

    // hoist phase-B A-frags (32 VGPR, live through phase B)
    bf16x8 WAh[4], WAl[4];
#pragma unroll
    for (int mt = 0; mt < 4; ++mt) {
        int off = ((mt * 16 + l15) * 32 + quad * 8) * 2;
        WAh[mt] = *(const bf16x8*)(ws + OFF_WA_H + off);
        WAl[mt] = *(const bf16x8*)(ws + OFF_WA_L + off);
    }
    __syncthreads();                         // intra-wave: HV/AT visible

    // ---- Phase B: 8 rows x 8 j = 64 pairs, 4 MFMA batches (2+2 preload) ----
    // pair = l15 within batch ii: nb = ii*2 + (l15>>3), j = l15&7
    const int jB  = l15 & 7;
    const int nbh = l15 >> 3;
#pragma unroll
    for (int pair = 0; pair < 2; ++pair) {
        float4 bv0[2], bv1[2];
#pragma unroll
        for (int k = 0; k < 2; ++k) {
            int nb = (pair * 2 + k) * 2 + nbh;
            const float* ap = act + (size_t)(n0 + nb) * 256 + jB * 32 + quad * 8;
            bv0[k] = ((const float4*)ap)[0];
            bv1[k] = ((const float4*)ap)[1];
        }
#pragma unroll
        for (int k = 0; k < 2; ++k) {
            int nb = (pair * 2 + k) * 2 + nbh;
            bf16x8 Bh, Bl;
            split8(bv0[k], bv1[k], Bh, Bl);
            f32x4 accB[4] = {zv, zv, zv, zv};
#pragma unroll
            for (int mt = 0; mt < 4; ++mt) {
                accB[mt] = MFMA(WAh[mt], Bh, accB[mt]);
                accB[mt] = MFMA(WAh[mt], Bl, accB[mt]);
                accB[mt] = MFMA(WAl[mt], Bh, accB[mt]);
            }
            float at = AT[nb * 8 + jB];
#pragma unroll
            for (int mt = 0; mt < 4; ++mt) {
                int d0 = mt * 16 + quad * 4;
                float4 hv4 = *(const float4*)&HV[jB * 68 + d0];   // h_rep row = j
                float r0 = at * fmaxf(accB[mt][0] + hv4.x, 0.f);
                float r1 = at * fmaxf(accB[mt][1] + hv4.y, 0.f);
                float r2 = at * fmaxf(accB[mt][2] + hv4.z, 0.f);
                float r3 = at * fmaxf(accB[mt][3] + hv4.w, 0.f);
#pragma unroll
                for (int m = 1; m <= 4; m <<= 1) {
                    r0 += __shfl_xor(r0, m);
                    r1 += __shfl_xor(r1, m);
                    r2 += __shfl_xor(r2, m);
                    r3 += __shfl_xor(r3, m);
                }
                if (jB == 0)                 // S row nb, d0..d0+3, bf16-packed
                    *(uint2*)&SS[nb * 72 + d0] = make_uint2(pk2(r0, r1), pk2(r2, r3));
            }
        }
    }

    // ---- W2 fragment loads (4KB shared, L1/L2-hot) ----
    float4 wva[4], wvb[4];                   // c = et*2 + kc
#pragma unroll
    for (int c = 0; c < 4; ++c) {
        const float* wp = wv2 + ((c >> 1) * 16 + l15) * 64 + (c & 1) * 32 + quad * 8;
        wva[c] = ((const float4*)wp)[0];
        wvb[c] = ((const float4*)wp)[1];
    }
    __syncthreads();                         // intra-wave: SS visible

    // ---- Wv2 via MFMA: out[8x32] = S[8x64] . W2^T (B cols 8-15 dup rows) ----
    {
        bf16x8 Sb[2];
#pragma unroll
        for (int kc = 0; kc < 2; ++kc)
            Sb[kc] = *(const bf16x8*)&SS[r8 * 72 + kc * 32 + quad * 8];
        f32x4 acc2[2] = {zv, zv};
#pragma unroll
        for (int c = 0; c < 4; ++c) {
            bf16x8 Ah, Al;
            split8(wva[c], wvb[c], Ah, Al);
            acc2[c >> 1] = MFMA(Ah, Sb[c & 1], acc2[c >> 1]);
            acc2[c >> 1] = MFMA(Al, Sb[c & 1], acc2[c >> 1]);
        }
        if (l15 < 8) {
#pragma unroll
            for (int et = 0; et < 2; ++et) {
                int e0 = et * 16 + quad * 4;
                float4 b = *(const float4*)&wv2b[e0];
                f32x4 a = acc2[et];
                *(float4*)&out[(size_t)(n0 + r8) * 32 + e0] =
                    make_float4(a[0] + b.x, a[1] + b.y, a[2] + b.z, a[3] + b.w);
            }
        }
    }
}

extern "C" void kernel_launch(void* const* d_in, const int* in_sizes, int n_in,
                              void* d_out, int out_size, void* d_ws, size_t ws_size,
                              hipStream_t stream) {
    const float* o     = (const float*)d_in[0];
    const float* onx   = (const float*)d_in[1];
    const float* h     = (const float*)d_in[2];
    const float* act   = (const float*)d_in[3];
    const float* wq_w  = (const float*)d_in[4];
    const float* wq_b  = (const float*)d_in[5];
    const float* wk_w  = (const float*)d_in[6];
    // d_in[7] = wk_b unused (softmax-invariant, diagonal masked)
    const float* wv1_w = (const float*)d_in[8];
    const float* wv1_b = (const float*)d_in[9];
    const float* wv2_w = (const float*)d_in[10];
    const float* wv2_b = (const float*)d_in[11];
    float* out = (float*)d_out;
    char* ws   = (char*)d_ws;   // needs ~105 KB

    k_setup<<<105, 256, 0, stream>>>(wq_w, wq_b, wk_w, wv1_w, ws);
    fused<<<8192, 64, 0, stream>>>(o, onx, h, act, wv1_b, wv2_w, wv2_b, ws, out);
}

// Round 8
// 233.761 us; speedup vs baseline: 1.6392x; 1.2987x over previous
//
#include <hip/hip_runtime.h>
#include <hip/hip_bf16.h>

// B=8192, A=8, OBS=128, NACT=32, H=256, D=64 ; N = 65536 rows
typedef __attribute__((ext_vector_type(8))) short bf16x8;   // 8 bf16 (4 VGPRs)
typedef __attribute__((ext_vector_type(4))) float f32x4;

#define MFMA(A, B, C) __builtin_amdgcn_mfma_f32_16x16x32_bf16((A), (B), (C), 0, 0, 0)

// ---- ws byte offsets: weights pre-split to bf16 hi/lo planes, [out][k] layout ----
// (lo planes still written by setup, no longer read: round 8 runs hi-only)
#define OFF_TB    0          // f32 [32]   folded t bias
#define OFF_WT_H  128        // bf16 [32][256]  Mt = SCALE*wk^T*wq
#define OFF_WT_L  16512
#define OFF_WHV_H 32896      // bf16 [64][256]  wv1 h-part
#define OFF_WHV_L 65664
#define OFF_WA_H  98432      // bf16 [64][32]   wv1 action-part
#define OFF_WA_L  102528     // end 106624

// ---- LDS (bytes), total 7168 (round-4 geometry: 16-row single-wave WG) ----
#define SM_HV   0        // f32 [16][68]    4352
#define SM_AT   4352     // f32 [16][8]      512
#define SM_SS   4864     // bf16 [16][72]   2304  (stride 72: rows 16B-aligned)
#define SM_TOT  7168

__device__ __forceinline__ unsigned short f2bf(float v) {   // RNE (setup only)
    unsigned u = __builtin_bit_cast(unsigned, v);
    return (unsigned short)((u + 0x7fffu + ((u >> 16) & 1u)) >> 16);
}
__device__ __forceinline__ float bf2f(unsigned short b) {
    return __builtin_bit_cast(float, ((unsigned)b) << 16);
}
__device__ __forceinline__ ushort2 splitf(float v) {        // (hi, lo residual)
    unsigned short h = f2bf(v);
    unsigned short l = f2bf(v - bf2f(h));
    return make_ushort2(h, l);
}

// __hip_bfloat162 -> u32 reinterpret (bit_cast rejects non-trivially-copyable)
__device__ __forceinline__ unsigned as_u32(__hip_bfloat162 v) {
    unsigned u;
    __builtin_memcpy(&u, &v, sizeof(u));
    return u;
}
__device__ __forceinline__ unsigned pk2(float x, float y) {  // v_cvt_pk_bf16_f32
    return as_u32(__float22bfloat162_rn(make_float2(x, y)));
}
// 8 floats -> bf16x8 (RNE), 4 cvt_pk instrs. Round 8: replaces split8
// (26 ops) — lo residual planes dropped everywhere (error analysis: final
// absmax est ~1e-3 < 2e-3 threshold; SS bf16 rounding already dominates).
__device__ __forceinline__ bf16x8 cvt8(float4 a, float4 b) {
    uint4 H;
    H.x = pk2(a.x, a.y);
    H.y = pk2(a.z, a.w);
    H.z = pk2(b.x, b.y);
    H.w = pk2(b.z, b.w);
    return __builtin_bit_cast(bf16x8, H);
}

// ---------------------------------------------------------------------------
// setup: fold Mt = SCALE*wk^T*wq (+bias), split weights into bf16 planes in
// fragment-native [out][k] layout. wk_b dropped (softmax-invariant, diagonal
// masked — verified round 1). Lo planes kept for layout stability (unread).
// ---------------------------------------------------------------------------
__global__ __launch_bounds__(256) void k_setup(const float* __restrict__ wq_w,
                                               const float* __restrict__ wq_b,
                                               const float* __restrict__ wk_w,
                                               const float* __restrict__ wv1,
                                               char* __restrict__ ws) {
    int gid = blockIdx.x * 256 + threadIdx.x;
    if (gid < 8192) {                              // Mt[k][c]
        int k = gid >> 8, c = gid & 255;
        float acc = 0.f;
#pragma unroll 8
        for (int d = 0; d < 64; ++d) acc = fmaf(wk_w[d * 32 + k], wq_w[d * 256 + c], acc);
        ushort2 s = splitf(0.125f * acc);
        ((unsigned short*)(ws + OFF_WT_H))[gid] = s.x;
        ((unsigned short*)(ws + OFF_WT_L))[gid] = s.y;
    } else if (gid < 24576) {                      // wv1 h-part [d][c]
        int i = gid - 8192;
        ushort2 s = splitf(wv1[(i >> 8) * 288 + (i & 255)]);
        ((unsigned short*)(ws + OFF_WHV_H))[i] = s.x;
        ((unsigned short*)(ws + OFF_WHV_L))[i] = s.y;
    } else if (gid < 26624) {                      // wv1 action-part [d][k]
        int i = gid - 24576;
        ushort2 s = splitf(wv1[(i >> 5) * 288 + 256 + (i & 31)]);
        ((unsigned short*)(ws + OFF_WA_H))[i] = s.x;
        ((unsigned short*)(ws + OFF_WA_L))[i] = s.y;
    } else if (gid < 26656) {                      // tb
        int k = gid - 26624;
        float b = 0.f;
#pragma unroll 8
        for (int d = 0; d < 64; ++d) b = fmaf(wk_w[d * 32 + k], wq_b[d], b);
        ((float*)(ws + OFF_TB))[k] = 0.125f * b;
    }
}

// ---------------------------------------------------------------------------
// Fused, block = ONE wave = 16 rows (2 batches) — round-4 geometry (best
// measured: 105 us). Round 8: plain-bf16 MFMA (hi planes only): MFMA/wave
// 248->84, weight loads halved, split8(26 ops)->cvt8(4 ops) on all act
// conversions. Occupancy structurally capped ~16 waves/CU; this attacks the
// per-wave critical path instead.
// ---------------------------------------------------------------------------
__global__ __launch_bounds__(64, 4) void fused(
    const float* __restrict__ o, const float* __restrict__ onx,
    const float* __restrict__ h, const float* __restrict__ act,
    const float* __restrict__ wv1b, const float* __restrict__ wv2,
    const float* __restrict__ wv2b, const char* __restrict__ ws,
    float* __restrict__ out)
{
    __shared__ __align__(16) char sm[SM_TOT];
    float* HV = (float*)(sm + SM_HV);               // [16][68]
    float* AT = (float*)(sm + SM_AT);               // [16][8]
    unsigned short* SS = (unsigned short*)(sm + SM_SS);  // [16][72]

    const int lane = threadIdx.x;          // 0..63
    const int l15  = lane & 15;
    const int quad = lane >> 4;
    const int n0   = blockIdx.x * 16;
    const int myrow = n0 + l15;            // phase-A fragment row of this lane

    const f32x4 zv = {0.f, 0.f, 0.f, 0.f};
    f32x4 acc_hv[4] = {zv, zv, zv, zv};
    f32x4 acc_t[2]  = {zv, zv};

    // ---- Phase A-x: preload all 8 chunks, then MFMA (hi-only) ----
    float4 xa[8], xb[8];
#pragma unroll
    for (int ch = 0; ch < 8; ++ch) {
        const float* src = (ch < 4)
            ? o   + (size_t)myrow * 128 + ch * 32 + quad * 8
            : onx + (size_t)myrow * 128 + (ch - 4) * 32 + quad * 8;
        xa[ch] = ((const float4*)src)[0];
        xb[ch] = ((const float4*)src)[1];
    }
#pragma unroll
    for (int ch = 0; ch < 8; ++ch) {
        bf16x8 Bh = cvt8(xa[ch], xb[ch]);
#pragma unroll
        for (int mt = 0; mt < 2; ++mt) {
            int off = ((mt * 16 + l15) * 256 + ch * 32 + quad * 8) * 2;
            bf16x8 Ah = *(const bf16x8*)(ws + OFF_WT_H + off);
            acc_t[mt] = MFMA(Ah, Bh, acc_t[mt]);
        }
    }
    // ---- Phase A-h: preload all 8 chunks, then MFMA (hi-only) ----
#pragma unroll
    for (int ch = 0; ch < 8; ++ch) {
        const float* src = h + (size_t)myrow * 256 + ch * 32 + quad * 8;
        xa[ch] = ((const float4*)src)[0];
        xb[ch] = ((const float4*)src)[1];
    }
#pragma unroll
    for (int ch = 0; ch < 8; ++ch) {
        bf16x8 Bh = cvt8(xa[ch], xb[ch]);
#pragma unroll
        for (int mt = 0; mt < 4; ++mt) {
            int off = ((mt * 16 + l15) * 256 + ch * 32 + quad * 8) * 2;
            bf16x8 Ah = *(const bf16x8*)(ws + OFF_WHV_H + off);
            acc_hv[mt] = MFMA(Ah, Bh, acc_hv[mt]);
        }
    }

    // ---- scores act preload (latency hides under HV epilogue) ----
    const float* arow = act + (size_t)myrow * 256;
    float4 av0[8], av1[8];
#pragma unroll
    for (int j = 0; j < 8; ++j) {
        av0[j] = *(const float4*)(arow + j * 32 + quad * 4);
        av1[j] = *(const float4*)(arow + j * 32 + 16 + quad * 4);
    }

    // ---- epilogue A: HV to LDS (col=l15 -> row n, row=quad*4+reg -> d) ----
#pragma unroll
    for (int mt = 0; mt < 4; ++mt) {
        int d0 = mt * 16 + quad * 4;
        float4 b = *(const float4*)&wv1b[d0];
        f32x4 a = acc_hv[mt];
        *(float4*)&HV[l15 * 68 + d0] =
            make_float4(a[0] + b.x, a[1] + b.y, a[2] + b.z, a[3] + b.w);
    }

    // ---- scores + softmax fully in-register ----
    {
        float t8[8];
        const float* tb = (const float*)(ws + OFF_TB);
#pragma unroll
        for (int mt = 0; mt < 2; ++mt) {
            float4 b = *(const float4*)&tb[mt * 16 + quad * 4];
            t8[mt * 4 + 0] = acc_t[mt][0] + b.x;
            t8[mt * 4 + 1] = acc_t[mt][1] + b.y;
            t8[mt * 4 + 2] = acc_t[mt][2] + b.z;
            t8[mt * 4 + 3] = acc_t[mt][3] + b.w;
        }
        float sc[8];
#pragma unroll
        for (int j = 0; j < 8; ++j) {
            float s = 0.f;
            s = fmaf(t8[0], av0[j].x, s);
            s = fmaf(t8[1], av0[j].y, s);
            s = fmaf(t8[2], av0[j].z, s);
            s = fmaf(t8[3], av0[j].w, s);
            s = fmaf(t8[4], av1[j].x, s);
            s = fmaf(t8[5], av1[j].y, s);
            s = fmaf(t8[6], av1[j].z, s);
            s = fmaf(t8[7], av1[j].w, s);
            sc[j] = s;
        }
#pragma unroll
        for (int j = 0; j < 8; ++j) {        // sum partials across the 4 quads
            sc[j] += __shfl_xor(sc[j], 16);
            sc[j] += __shfl_xor(sc[j], 32);
        }
        const int diag = l15 & 7;            // row mod 8 (n0 is 16-aligned)
        float mx = -1e30f;
#pragma unroll
        for (int j = 0; j < 8; ++j) if (j != diag) mx = fmaxf(mx, sc[j]);
        float ex[8], sum = 0.f;
#pragma unroll
        for (int j = 0; j < 8; ++j) {
            ex[j] = (j == diag) ? 0.f : __expf(sc[j] - mx);
            sum += ex[j];
        }
        float inv = 1.f / sum;
        if (quad == 0) {                     // one writer per row
            *(float4*)&AT[l15 * 8] =
                make_float4(ex[0] * inv, ex[1] * inv, ex[2] * inv, ex[3] * inv);
            *(float4*)&AT[l15 * 8 + 4] =
                make_float4(ex[4] * inv, ex[5] * inv, ex[6] * inv, ex[7] * inv);
        }
    }

    // hoist phase-B A-frags (hi-only: 16 VGPR)
    bf16x8 WAh[4];
#pragma unroll
    for (int mt = 0; mt < 4; ++mt) {
        int off = ((mt * 16 + l15) * 32 + quad * 8) * 2;
        WAh[mt] = *(const bf16x8*)(ws + OFF_WA_H + off);
    }
    __syncthreads();                         // intra-wave: HV/AT visible

    // ---- Phase B: 16 rows x 8 j = 128 pairs ----
    // nb = nt*2 + (l15>>3), j = l15&7 (j constant per lane across nt)
    const int jB  = l15 & 7;
    const int nbh = l15 >> 3;
#pragma unroll
    for (int half = 0; half < 2; ++half) {
        float4 bv0[4], bv1[4];
#pragma unroll
        for (int ii = 0; ii < 4; ++ii) {
            int nb = (half * 4 + ii) * 2 + nbh;
            const float* ap = act + (size_t)(n0 + nb) * 256 + jB * 32 + quad * 8;
            bv0[ii] = ((const float4*)ap)[0];
            bv1[ii] = ((const float4*)ap)[1];
        }
#pragma unroll
        for (int ii = 0; ii < 4; ++ii) {
            int nb = (half * 4 + ii) * 2 + nbh;
            bf16x8 Bh = cvt8(bv0[ii], bv1[ii]);
            f32x4 accB[4] = {zv, zv, zv, zv};
#pragma unroll
            for (int mt = 0; mt < 4; ++mt)
                accB[mt] = MFMA(WAh[mt], Bh, accB[mt]);
            int hrow = (nb & 8) + jB;        // h_rep row within wave's 16 rows
            float at = AT[nb * 8 + jB];
#pragma unroll
            for (int mt = 0; mt < 4; ++mt) {
                int d0 = mt * 16 + quad * 4;
                float4 hv4 = *(const float4*)&HV[hrow * 68 + d0];
                float r0 = at * fmaxf(accB[mt][0] + hv4.x, 0.f);
                float r1 = at * fmaxf(accB[mt][1] + hv4.y, 0.f);
                float r2 = at * fmaxf(accB[mt][2] + hv4.z, 0.f);
                float r3 = at * fmaxf(accB[mt][3] + hv4.w, 0.f);
#pragma unroll
                for (int m = 1; m <= 4; m <<= 1) {
                    r0 += __shfl_xor(r0, m);
                    r1 += __shfl_xor(r1, m);
                    r2 += __shfl_xor(r2, m);
                    r3 += __shfl_xor(r3, m);
                }
                if (jB == 0)                 // S row nb, d0..d0+3, bf16-packed
                    *(uint2*)&SS[nb * 72 + d0] = make_uint2(pk2(r0, r1), pk2(r2, r3));
            }
        }
    }

    // ---- W2 fragment loads (4KB shared, L1/L2-hot) ----
    float4 wva[4], wvb[4];                   // c = et*2 + kc
#pragma unroll
    for (int c = 0; c < 4; ++c) {
        const float* wp = wv2 + ((c >> 1) * 16 + l15) * 64 + (c & 1) * 32 + quad * 8;
        wva[c] = ((const float4*)wp)[0];
        wvb[c] = ((const float4*)wp)[1];
    }
    __syncthreads();                         // intra-wave: SS visible

    // ---- Wv2 via MFMA (hi-only): out[16x32] = S[16x64] . W2^T ----
    {
        bf16x8 Sb[2];
#pragma unroll
        for (int kc = 0; kc < 2; ++kc)
            Sb[kc] = *(const bf16x8*)&SS[l15 * 72 + kc * 32 + quad * 8];
        f32x4 acc2[2] = {zv, zv};
#pragma unroll
        for (int c = 0; c < 4; ++c) {
            bf16x8 Ah = cvt8(wva[c], wvb[c]);
            acc2[c >> 1] = MFMA(Ah, Sb[c & 1], acc2[c >> 1]);
        }
#pragma unroll
        for (int et = 0; et < 2; ++et) {
            int e0 = et * 16 + quad * 4;
            float4 b = *(const float4*)&wv2b[e0];
            f32x4 a = acc2[et];
            *(float4*)&out[(size_t)(n0 + l15) * 32 + e0] =
                make_float4(a[0] + b.x, a[1] + b.y, a[2] + b.z, a[3] + b.w);
        }
    }
}

extern "C" void kernel_launch(void* const* d_in, const int* in_sizes, int n_in,
                              void* d_out, int out_size, void* d_ws, size_t ws_size,
                              hipStream_t stream) {
    const float* o     = (const float*)d_in[0];
    const float* onx   = (const float*)d_in[1];
    const float* h     = (const float*)d_in[2];
    const float* act   = (const float*)d_in[3];
    const float* wq_w  = (const float*)d_in[4];
    const float* wq_b  = (const float*)d_in[5];
    const float* wk_w  = (const float*)d_in[6];
    // d_in[7] = wk_b unused (softmax-invariant, diagonal masked)
    const float* wv1_w = (const float*)d_in[8];
    const float* wv1_b = (const float*)d_in[9];
    const float* wv2_w = (const float*)d_in[10];
    const float* wv2_b = (const float*)d_in[11];
    float* out = (float*)d_out;
    char* ws   = (char*)d_ws;   // needs ~105 KB

    k_setup<<<105, 256, 0, stream>>>(wq_w, wq_b, wk_w, wv1_w, ws);
    fused<<<4096, 64, 0, stream>>>(o, onx, h, act, wv1_b, wv2_w, wv2_b, ws, out);
}